// Round 9
// baseline (162.255 us; speedup 1.0000x reference)
//
#include <hip/hip_runtime.h>
#include <hip/hip_bf16.h>
#include <math.h>

// Problem constants (match reference)
#define BB  32
#define SS  4096
#define VV  256
#define DD  256
#define CC  2
#define WIN 64
#define NW  64   // SS/WIN

typedef unsigned short ushort_t;
typedef unsigned int   uint_t;
typedef _Float16 half_t;
typedef __attribute__((ext_vector_type(8))) _Float16 half8;   // 8 f16 (4 VGPRs)
typedef __attribute__((ext_vector_type(4))) float f32x4;

// Workspace layout (byte offsets). Total 303104 B (fits prior 573440 ws).
#define WS_A16_B  0u          // half A16[64][64]     8192  (A-op layout: [t][s])
#define WS_G16_B  8192u       // half g16[256][256]   131072
#define WS_W216_B 139264u     // half W216[256][256]  131072
#define WS_POOL_B 270336u     // float pool[32][256]  32768

#define HP 264    // H plane row stride in halfs (256 + 8 pad; row = 528 B = 33*16)

__device__ __forceinline__ float fast_tanh(float v) {
  float e = __expf(2.0f * v);
  return 1.0f - __fdividef(2.0f, e + 1.0f);
}

union u4h8 { uint_t u[4]; half8 v; };

// ---------------------------------------------------------------------------
// Prep grid (1090 blocks): unchanged from round 7 (fp16 planes, verified).
// ---------------------------------------------------------------------------
__global__ __launch_bounds__(256) void prep_kernel(
    const float* __restrict__ emb, const float* __restrict__ W1,
    const float* __restrict__ W2, char* __restrict__ ws)
{
  const int blk = blockIdx.x;
  const int tid = threadIdx.x;
  half_t* A16  = (half_t*)(ws + WS_A16_B);
  half_t* g16  = (half_t*)(ws + WS_G16_B);
  half_t* W216 = (half_t*)(ws + WS_W216_B);
  float*  pool = (float*) (ws + WS_POOL_B);

  if (blk == 0) {
    if (tid < WIN) {
      const int s = tid;
      const float omega = 60.0f * 2.0f * 3.14159265358979323846f / 4095.0f;
      float row[WIN];
      float sum = 0.0f;
      for (int t = 0; t < WIN; ++t) {
        float e = expf(cosf(omega * (float)(s - t)));
        row[t] = e;
        sum += e;
      }
      const float inv = 1.0f / sum;
      for (int t = 0; t < WIN; ++t)
        A16[t * WIN + s] = (half_t)(row[t] * inv);
    }
  } else if (blk == 1) {
    for (int i = tid; i < BB * DD; i += 256) pool[i] = 0.0f;
  } else if (blk < 1026) {
    const int gv = blk - 2;            // 0..1023
    const int d0 = (gv & 15) * 16;     // 16 d-columns
    const int v0 = (gv >> 4) * 4;      // 4 v-rows
    __shared__ float er[4 * DD];       // 4 KB
    __shared__ float ps[4][16][17];    // padded partials
    *(float4*)(er + tid * 4) = *(const float4*)(emb + v0 * DD + tid * 4);
    __syncthreads();
    const int kq = tid & 15;           // k-strip: [16kq, 16kq+16)
    const int dl = tid >> 4;           // 0..15
    const int d  = d0 + dl;
    float4 wv[4];
    #pragma unroll
    for (int j = 0; j < 4; ++j)
      wv[j] = *(const float4*)(W1 + d * DD + 16 * kq + 4 * j);  // coalesced
    #pragma unroll
    for (int v = 0; v < 4; ++v) {
      float a = 0.0f;
      #pragma unroll
      for (int j = 0; j < 4; ++j) {
        float4 e = *(const float4*)(er + v * DD + 16 * kq + 4 * j);
        a += e.x * wv[j].x + e.y * wv[j].y + e.z * wv[j].z + e.w * wv[j].w;
      }
      ps[v][dl][kq] = a;
    }
    __syncthreads();
    if (tid < 64) {
      const int v = tid >> 4, dr = tid & 15;
      float s = 0.0f;
      #pragma unroll
      for (int k = 0; k < 16; ++k) s += ps[v][dr][k];
      g16[(v0 + v) * DD + d0 + dr] = (half_t)s;
    }
  } else {
    const int c0 = (blk - 1026) * 4;
    #pragma unroll
    for (int i = 0; i < 4; ++i) {
      const int c = c0 + i;
      W216[c * DD + tid] = (half_t)W2[c * DD + tid];
    }
  }
}

// ---------------------------------------------------------------------------
// Main fused kernel — round-7 fp16 structure, ONE change: P4 split into two
// half-passes (mt {0,1} then {2,3}) with acc2[2][2] (16 accs, was 32).
// Rationale: round-8 showed total per-wave alloc ~88 (arch 40 + acc ~48)
// > 85 = 512/6, pinning residency at 5 waves/SIMD -> 2 blocks/CU while
// VALU (the critical pipe, 66% busy) has 1.5x headroom. Halving acc2 puts
// total ~66-72 -> 7 waves/SIMD -> 3 blocks/CU (LDS 34.3KB*3=103KB fits).
// Pass 2 drops the flag polls (pass 1 already acquired all 8 slices).
// pres accumulation order: pass0 adds mt0,mt1; pass1 adds mt2,mt3 ==
// identical to the previous mt0..3 loop -> bit-identical output.
// Cost: W2 frag loads x2 (L1-hot), H ds_reads x2 (~3% issue). Tripwires:
// WRITE_SIZE ~2 MB, absmax == 7.629e-6.
// ---------------------------------------------------------------------------
__global__ __launch_bounds__(512, 6) void main_kernel(
    const int*      __restrict__ x,    const ushort_t* __restrict__ g16u,
    const half_t*   __restrict__ A16,  const float*    __restrict__ b1,
    const half_t*   __restrict__ W216, const float*    __restrict__ b2,
    float* __restrict__ pool)
{
  __shared__ half_t H16[WIN][HP];     // 33792 B
  __shared__ int ready[8];            // per-wave d-slice published flags

  const int tid  = threadIdx.x;
  const int lane = tid & 63;
  const int w    = tid >> 6;       // 0..7
  const int quad = lane >> 4;
  const int l16  = lane & 15;
  const int b = blockIdx.x >> 6;
  const int n = blockIdx.x & 63;

  const int dbase = 32 * w;        // this wave's d-slice (P2) == c-slice (P4)
  const int cbase = dbase;
  const int rsw   = (l16 & 8) << 1;   // P4 read un-swizzle (16 halfs)

  if (tid < 8) ready[tid] = 0;

  // --- P1: gather (fp16, ushort loads), issued first to overlap setup ---
  const int xv = x[b * SS + n * WIN + lane];
  uint_t q[2][2][8];
  #pragma unroll
  for (int k0 = 0; k0 < 2; ++k0) {
    const int sl = k0 * 32 + quad * 8;
    int xs[8];
    #pragma unroll
    for (int j = 0; j < 8; ++j) xs[j] = __shfl(xv, sl + j, 64);
    #pragma unroll
    for (int nt = 0; nt < 2; ++nt) {
      const int d = dbase + 16 * nt + l16;
      #pragma unroll
      for (int j = 0; j < 8; ++j) q[k0][nt][j] = (uint_t)g16u[xs[j] * DD + d];
    }
  }

  float b1v[2], b2v[2];
  #pragma unroll
  for (int nt = 0; nt < 2; ++nt) {
    b1v[nt] = b1[dbase + 16 * nt + l16];
    b2v[nt] = b2[cbase + 16 * nt + l16];
  }

  __syncthreads();   // flags zeroed before any wave can publish

  // Build B-fragments (q dies here): pack pairs with one lshl_or each.
  half8 bf[2][2];
  #pragma unroll
  for (int k0 = 0; k0 < 2; ++k0)
    #pragma unroll
    for (int nt = 0; nt < 2; ++nt) {
      u4h8 h;
      #pragma unroll
      for (int p = 0; p < 4; ++p)
        h.u[p] = q[k0][nt][2 * p] | (q[k0][nt][2 * p + 1] << 16);
      bf[k0][nt] = h.v;
    }

  // --- P2+P3 fused, mt-outer: MFMA tile then its tanh/cvt/store ---
  #pragma unroll
  for (int mt = 0; mt < 4; ++mt) {
    f32x4 a1[2];
    a1[0] = (f32x4)0.0f;
    a1[1] = (f32x4)0.0f;
    #pragma unroll
    for (int k0 = 0; k0 < 2; ++k0) {
      const int sl = k0 * 32 + quad * 8;
      const int t  = mt * 16 + l16;
      half8 ah = *(const half8*)(A16 + t * WIN + sl);   // L1-resident
      #pragma unroll
      for (int nt = 0; nt < 2; ++nt)
        a1[nt] = __builtin_amdgcn_mfma_f32_16x16x32_f16(ah, bf[k0][nt], a1[nt], 0, 0, 0);
    }
    // P3 for this mt: tanh(+b1), cvt f16, swizzled store.
    const int wsw = (quad & 2) << 3;    // row-bit3 of tl -> XOR 16 halfs
    #pragma unroll
    for (int nt = 0; nt < 2; ++nt) {
      const int ds = (dbase + 16 * nt + l16) ^ wsw;
      #pragma unroll
      for (int r = 0; r < 4; ++r) {
        const int tl = mt * 16 + quad * 4 + r;
        H16[tl][ds] = (half_t)fast_tanh(a1[nt][r] + b1v[nt]);
      }
    }
  }

  // Publish this wave's d-slice (release: drains the ds_writes first).
  __hip_atomic_store(&ready[w], 1, __ATOMIC_RELEASE, __HIP_MEMORY_SCOPE_WORKGROUP);

  // --- P4+P5: two half-passes (mt pair per pass), acc2[2][2] = 16 accs ---
  float pres[2];
  pres[0] = 0.0f;
  pres[1] = 0.0f;

  #pragma unroll
  for (int hp = 0; hp < 2; ++hp) {
    f32x4 acc2[2][2];
    #pragma unroll
    for (int m2 = 0; m2 < 2; ++m2)
      #pragma unroll
      for (int nt = 0; nt < 2; ++nt) acc2[m2][nt] = (f32x4)0.0f;

    half8 wf[2][2];
    {
      const int dsl0 = w * 32 + quad * 8;   // first k0 = own slice
      #pragma unroll
      for (int nt = 0; nt < 2; ++nt) {
        const int c = cbase + 16 * nt + l16;
        wf[0][nt] = *(const half8*)(W216 + c * DD + dsl0);
      }
    }

    #pragma unroll 2
    for (int kk = 0; kk < 8; ++kk) {
      const int k0  = (w + kk) & 7;
      const int cur = kk & 1, nxt = cur ^ 1;
      if (kk < 7) {
        const int dsln = ((w + kk + 1) & 7) * 32 + quad * 8;
        #pragma unroll
        for (int nt = 0; nt < 2; ++nt) {
          const int c = cbase + 16 * nt + l16;
          wf[nxt][nt] = *(const half8*)(W216 + c * DD + dsln);   // prefetch kk+1
        }
      }
      // Poll only in pass 0 (pass 1: all 8 slices already acquired).
      if (hp == 0) {
        while (__hip_atomic_load(&ready[k0], __ATOMIC_ACQUIRE,
                                 __HIP_MEMORY_SCOPE_WORKGROUP) == 0) { }
      }
      const int dsw = (k0 * 32 + quad * 8) ^ rsw;   // un-swizzled read col
      __builtin_amdgcn_s_setprio(1);
      #pragma unroll
      for (int m2 = 0; m2 < 2; ++m2) {
        const int t = (hp * 2 + m2) * 16 + l16;
        half8 ah = *(const half8*)(&H16[t][dsw]);   // ds_read_b128
        #pragma unroll
        for (int nt = 0; nt < 2; ++nt)
          acc2[m2][nt] = __builtin_amdgcn_mfma_f32_16x16x32_f16(ah, wf[cur][nt], acc2[m2][nt], 0, 0, 0);
      }
      __builtin_amdgcn_s_setprio(0);
    }

    // P5 partial for this half: tanh(+b2) + token-sum into pres regs.
    // Order: pass0 adds mt0,mt1; pass1 adds mt2,mt3 == original mt0..3.
    #pragma unroll
    for (int nt = 0; nt < 2; ++nt) {
      #pragma unroll
      for (int m2 = 0; m2 < 2; ++m2)
        #pragma unroll
        for (int r = 0; r < 4; ++r)
          pres[nt] += fast_tanh(acc2[m2][nt][r] + b2v[nt]);
    }
  }

  // --- epilogue: reduce + one atomic per (b,c) ---
  #pragma unroll
  for (int nt = 0; nt < 2; ++nt) {
    float p = pres[nt];
    p += __shfl_xor(p, 16, 64);
    p += __shfl_xor(p, 32, 64);
    if (quad == 0) atomicAdd(&pool[b * DD + cbase + 16 * nt + l16], p);
  }
}

// ---------------------------------------------------------------------------
// Final: out[b,c] = (pool[b,:] / S) . Wc[c,:] + bc[c].  One block per b.
// ---------------------------------------------------------------------------
__global__ __launch_bounds__(64) void final_kernel(
    const float* __restrict__ pool, const float* __restrict__ Wc,
    const float* __restrict__ bc, float* __restrict__ out)
{
  const int b = blockIdx.x;
  const int t = threadIdx.x;
  float p0 = 0.0f, p1 = 0.0f;
  #pragma unroll
  for (int j = 0; j < 4; ++j) {
    float pv = pool[b * DD + t + 64 * j];
    p0 += pv * Wc[t + 64 * j];
    p1 += pv * Wc[DD + t + 64 * j];
  }
  #pragma unroll
  for (int off = 32; off; off >>= 1) {
    p0 += __shfl_xor(p0, off, 64);
    p1 += __shfl_xor(p1, off, 64);
  }
  if (t == 0) {
    out[b * CC + 0] = p0 * (1.0f / SS) + bc[0];
    out[b * CC + 1] = p1 * (1.0f / SS) + bc[1];
  }
}

extern "C" void kernel_launch(void* const* d_in, const int* in_sizes, int n_in,
                              void* d_out, int out_size, void* d_ws, size_t ws_size,
                              hipStream_t stream) {
  const int*   x   = (const int*)  d_in[0];
  const float* emb = (const float*)d_in[1];
  const float* W1  = (const float*)d_in[2];
  const float* b1  = (const float*)d_in[3];
  const float* W2  = (const float*)d_in[4];
  const float* b2  = (const float*)d_in[5];
  const float* Wc  = (const float*)d_in[6];
  const float* bc  = (const float*)d_in[7];
  float* out = (float*)d_out;
  char*  ws  = (char*)d_ws;

  prep_kernel<<<1090, 256, 0, stream>>>(emb, W1, W2, ws);
  main_kernel<<<BB * NW, 512, 0, stream>>>(
      x,
      (const ushort_t*)(ws + WS_G16_B),
      (const half_t*)  (ws + WS_A16_B),
      b1,
      (const half_t*)  (ws + WS_W216_B),
      b2,
      (float*)(ws + WS_POOL_B));
  final_kernel<<<BB, 64, 0, stream>>>((const float*)(ws + WS_POOL_B), Wc, bc, out);
}